// Round 1
// baseline (191.423 us; speedup 1.0000x reference)
//
#include <hip/hip_runtime.h>
#include <hip/hip_cooperative_groups.h>

namespace cg = cooperative_groups;

#define BATCH 4
#define T 4096
#define D 128
#define CHUNKS 64              // gram chunks per batch (64 rows each)
#define ROWS 64                // rows per block (gram and xg phases share the chunk)
#define ST1 72                 // XT LDS stride in ushorts (144 B = 36 words == 4 mod 32)
#define S2 136                 // row-major LDS stride in ushorts (272 B = 68 words == 4 mod 32)

typedef __attribute__((ext_vector_type(4))) float f32x4;
typedef __attribute__((ext_vector_type(8))) short bf16x8;

// float -> bf16 bits, round-to-nearest-even
__device__ __forceinline__ unsigned short f2b(float f) {
    unsigned u = __builtin_bit_cast(unsigned, f);
    u += 0x7FFFu + ((u >> 16) & 1u);
    return (unsigned short)(u >> 16);
}
__device__ __forceinline__ float b2f(unsigned short h) {
    return __builtin_bit_cast(float, (unsigned)h << 16);
}

// Single cooperative kernel: 256 blocks x 256 threads, 1 block/CU.
// Phase A: partial Gram (proven k_gram) + row-major Xs staging piggybacked
//          on the same global loads (x read from HBM exactly once).
// Phase B: reduce 64 bf16 partials -> bf16 G (proven k_reduce_g).
// Phase C: out = X*G (proven k_xg_mfma), Xs already resident in LDS,
//          Gs overlays the XT region.
__global__ __launch_bounds__(256) void k_fused(const float* __restrict__ x,
                                               unsigned short* __restrict__ part,
                                               unsigned short* __restrict__ g,
                                               float* __restrict__ out) {
    __shared__ unsigned short Xs[ROWS * S2];   // 17.0 KB, written phase A, read phase C
    __shared__ unsigned short XG[D * S2];      // 34.0 KB: XT (phase A) then Gs (phase C)

    const int blk = blockIdx.x;
    const int b = blk >> 6, chunk = blk & 63;
    const float* xp = x + ((size_t)b * T + (size_t)chunk * ROWS) * D;
    const int tid = threadIdx.x;
    const int lane = tid & 63, w = tid >> 6;
    const int m = lane & 15, q = lane >> 4;

    // ---------------- Phase A: partial Gram via bf16 MFMA ----------------
    unsigned short* XT = XG;
    #pragma unroll
    for (int pass = 0; pass < 8; pass++) {
        const int slot = (tid >> 6) + 4 * pass;            // 0..31
        const int dd = 2 * (tid & 7) + 16 * (slot & 7);    // even d base, 0..126
        const int tpg = ((tid >> 3) & 7) + 8 * (slot >> 3);// t-pair 0..31
        const int t = 2 * tpg;
        float2 f0 = *(const float2*)(xp + (size_t)t * D + dd);
        float2 f1 = *(const float2*)(xp + (size_t)(t + 1) * D + dd);
        const unsigned short b00 = f2b(f0.x), b01 = f2b(f0.y);
        const unsigned short b10 = f2b(f1.x), b11 = f2b(f1.y);
        // transposed XT[d][t] for the Gram MFMA (banks: 2-way, free)
        *(unsigned*)(XT + dd * ST1 + 2 * tpg)       = (unsigned)b00 | ((unsigned)b10 << 16);
        *(unsigned*)(XT + (dd + 1) * ST1 + 2 * tpg) = (unsigned)b01 | ((unsigned)b11 << 16);
        // row-major Xs[t][d] for phase C (word = 136*tpg + dd/2 -> 2-way, free)
        *(unsigned*)(Xs + (size_t)t * S2 + dd)       = (unsigned)b00 | ((unsigned)b01 << 16);
        *(unsigned*)(Xs + (size_t)(t + 1) * S2 + dd) = (unsigned)b10 | ((unsigned)b11 << 16);
    }
    __syncthreads();

    {
        const int m0 = w * 32;
        f32x4 acc[2][8];
        #pragma unroll
        for (int mi = 0; mi < 2; mi++)
            #pragma unroll
            for (int ni = 0; ni < 8; ni++) acc[mi][ni] = (f32x4){0.f, 0.f, 0.f, 0.f};

        #pragma unroll
        for (int s = 0; s < 2; s++) {            // k0 = s*32
            bf16x8 av[2], bv[8];
            #pragma unroll
            for (int mi = 0; mi < 2; mi++)
                av[mi] = *(const bf16x8*)(XT + (m0 + mi * 16 + m) * ST1 + q * 8 + s * 32);
            #pragma unroll
            for (int ni = 0; ni < 8; ni++)
                bv[ni] = *(const bf16x8*)(XT + (ni * 16 + m) * ST1 + q * 8 + s * 32);
            #pragma unroll
            for (int mi = 0; mi < 2; mi++)
                #pragma unroll
                for (int ni = 0; ni < 8; ni++)
                    acc[mi][ni] = __builtin_amdgcn_mfma_f32_16x16x32_bf16(av[mi], bv[ni], acc[mi][ni], 0, 0, 0);
        }

        // Store partial G (bf16). C/D layout: col=lane&15, row=q*4+reg (m89/m91).
        unsigned short* pp = part + (size_t)blk * (D * D);
        #pragma unroll
        for (int mi = 0; mi < 2; mi++)
            #pragma unroll
            for (int ni = 0; ni < 8; ni++) {
                const int row0 = m0 + mi * 16 + q * 4;
                const int col = ni * 16 + m;
                #pragma unroll
                for (int r = 0; r < 4; r++)
                    pp[(size_t)(row0 + r) * D + col] = f2b(acc[mi][ni][r]);
            }
    }

    __threadfence();            // device-scope release of part (cross-XCD)
    cg::this_grid().sync();

    // ---------------- Phase B: reduce bf16 partials -> bf16 G ----------------
    {
        const int o = blk * 256 + tid;           // 0 .. BATCH*D*D
        const int bb = o >> 14;
        const int e = o & 16383;
        const unsigned short* p = part + ((size_t)bb * CHUNKS) * (D * D) + e;
        float s[8];
        #pragma unroll
        for (int i = 0; i < 8; i++) s[i] = 0.f;
        for (int c = 0; c < CHUNKS; c += 8) {
            #pragma unroll
            for (int i = 0; i < 8; i++)
                s[i] += b2f(p[(size_t)(c + i) * (D * D)]);
        }
        float sum = ((s[0] + s[1]) + (s[2] + s[3])) + ((s[4] + s[5]) + (s[6] + s[7]));
        g[o] = f2b(sum);
    }

    __threadfence();            // device-scope release of g (cross-XCD)
    cg::this_grid().sync();

    // ---------------- Phase C: out = X * G via bf16 MFMA ----------------
    unsigned short* Gs = XG;    // overlays XT (dead since phase A)
    {
        const unsigned short* gp = g + (size_t)b * (D * D);
        const int f4 = tid & 15, r = tid >> 4;
        #pragma unroll
        for (int ii = 0; ii < 8; ii++) {
            const int row = r + ii * 16;
            uint4 gv = ((const uint4*)(gp + row * D))[f4];
            *(uint4*)(Gs + row * S2 + f4 * 8) = gv;
        }
    }
    __syncthreads();

    {
        f32x4 acc[8];
        #pragma unroll
        for (int ni = 0; ni < 8; ni++) acc[ni] = (f32x4){0.f, 0.f, 0.f, 0.f};

        const unsigned short* arow = Xs + (w * 16 + m) * S2 + q * 8;
        const unsigned short* brow = Gs + m * S2 + q * 8;

        #pragma unroll
        for (int s = 0; s < 4; s++) {
            bf16x8 a = *(const bf16x8*)(arow + s * 32);
            #pragma unroll
            for (int ni = 0; ni < 8; ni++) {
                bf16x8 bb = *(const bf16x8*)(brow + ni * 16 * S2 + s * 32);
                acc[ni] = __builtin_amdgcn_mfma_f32_16x16x32_bf16(a, bb, acc[ni], 0, 0, 0);
            }
        }

        float* op = out + ((size_t)b * T + (size_t)chunk * ROWS) * D;
        const int row0 = w * 16 + q * 4;
        #pragma unroll
        for (int ni = 0; ni < 8; ni++)
            #pragma unroll
            for (int r = 0; r < 4; r++)
                op[(row0 + r) * D + ni * 16 + m] = acc[ni][r];
    }
}

extern "C" void kernel_launch(void* const* d_in, const int* in_sizes, int n_in,
                              void* d_out, int out_size, void* d_ws, size_t ws_size,
                              hipStream_t stream) {
    const float* x = (const float*)d_in[0];
    float* out = (float*)d_out;

    const size_t part_elems = (size_t)BATCH * CHUNKS * D * D;   // 4.19M bf16 (8.4 MB)
    unsigned short* part = (unsigned short*)d_ws;
    unsigned short* g = part + part_elems;                      // bf16 G, 128 KB

    void* args[4] = {(void*)&x, (void*)&part, (void*)&g, (void*)&out};
    hipLaunchCooperativeKernel(reinterpret_cast<void*>(k_fused),
                               dim3(BATCH * CHUNKS), dim3(256), args, 0, stream);
}

// Round 2
// 126.726 us; speedup vs baseline: 1.5105x; 1.5105x over previous
//
#include <hip/hip_runtime.h>

#define BATCH 4
#define T 4096
#define D 128
#define CHUNKS 64              // gram chunks per batch (64 rows each)
#define ROWS 64                // rows per block (gram and xg phases share the chunk)
#define ST1 72                 // XT LDS stride in ushorts (144 B = 36 words == 4 mod 32)
#define S2 136                 // row-major LDS stride in ushorts (272 B = 68 words == 4 mod 32)

typedef __attribute__((ext_vector_type(4))) float f32x4;
typedef __attribute__((ext_vector_type(8))) short bf16x8;

// float -> bf16 bits, round-to-nearest-even
__device__ __forceinline__ unsigned short f2b(float f) {
    unsigned u = __builtin_bit_cast(unsigned, f);
    u += 0x7FFFu + ((u >> 16) & 1u);
    return (unsigned short)(u >> 16);
}
__device__ __forceinline__ float b2f(unsigned short h) {
    return __builtin_bit_cast(float, (unsigned)h << 16);
}

// Hand-rolled 64-block barrier (per-batch). All 256 blocks are co-resident
// (1 block/CU, proven by the cooperative launch of identical geometry), so
// spinning cannot deadlock. Thread 0 arrives with an agent-scope atomicAdd
// (release: flushes this XCD's dirty lines) and spins with acquire loads
// (invalidates L1/L2 per the gfx950 memory model) + s_sleep backoff.
__device__ __forceinline__ void batch_barrier(unsigned* c, unsigned expected) {
    __syncthreads();
    if (threadIdx.x == 0) {
        __threadfence();  // release prior global writes (device scope)
        __hip_atomic_fetch_add(c, 1u, __ATOMIC_ACQ_REL, __HIP_MEMORY_SCOPE_AGENT);
        for (;;) {
            unsigned v = __hip_atomic_load(c, __ATOMIC_ACQUIRE, __HIP_MEMORY_SCOPE_AGENT);
            if (v >= expected) break;
            __builtin_amdgcn_s_sleep(2);
        }
        __threadfence();  // acquire: invalidate caches before consuming peers' data
    }
    __syncthreads();
}

// Single persistent kernel: 256 blocks x 256 threads, 1 block/CU.
// Phase A: partial Gram (proven k_gram) + row-major Xs staging piggybacked
//          on the same global loads (x read from HBM exactly once).
// Phase B: reduce 64 bf16 partials -> bf16 G (proven k_reduce_g).
// Phase C: out = X*G (proven k_xg_mfma), Xs already resident in LDS,
//          Gs overlays the XT region. Both inter-phase dependencies are
//          batch-local (64 blocks), handled by batch_barrier.
__global__ __launch_bounds__(256) void k_fused(const float* __restrict__ x,
                                               unsigned short* __restrict__ part,
                                               unsigned short* __restrict__ g,
                                               unsigned* __restrict__ ctr,
                                               float* __restrict__ out) {
    __shared__ unsigned short Xs[ROWS * S2];   // 17.0 KB, written phase A, read phase C
    __shared__ unsigned short XG[D * S2];      // 34.0 KB: XT (phase A) then Gs (phase C)

    const int blk = blockIdx.x;
    const int b = blk >> 6, chunk = blk & 63;
    const float* xp = x + ((size_t)b * T + (size_t)chunk * ROWS) * D;
    const int tid = threadIdx.x;
    const int lane = tid & 63, w = tid >> 6;
    const int m = lane & 15, q = lane >> 4;

    // ---------------- Phase A: partial Gram via bf16 MFMA ----------------
    unsigned short* XT = XG;
    #pragma unroll
    for (int pass = 0; pass < 8; pass++) {
        const int slot = (tid >> 6) + 4 * pass;            // 0..31
        const int dd = 2 * (tid & 7) + 16 * (slot & 7);    // even d base, 0..126
        const int tpg = ((tid >> 3) & 7) + 8 * (slot >> 3);// t-pair 0..31
        const int t = 2 * tpg;
        float2 f0 = *(const float2*)(xp + (size_t)t * D + dd);
        float2 f1 = *(const float2*)(xp + (size_t)(t + 1) * D + dd);
        const unsigned short b00 = f2b(f0.x), b01 = f2b(f0.y);
        const unsigned short b10 = f2b(f1.x), b11 = f2b(f1.y);
        // transposed XT[d][t] for the Gram MFMA (banks: 2-way, free)
        *(unsigned*)(XT + dd * ST1 + 2 * tpg)       = (unsigned)b00 | ((unsigned)b10 << 16);
        *(unsigned*)(XT + (dd + 1) * ST1 + 2 * tpg) = (unsigned)b01 | ((unsigned)b11 << 16);
        // row-major Xs[t][d] for phase C (word = 136*tpg + dd/2 -> 2-way, free)
        *(unsigned*)(Xs + (size_t)t * S2 + dd)       = (unsigned)b00 | ((unsigned)b01 << 16);
        *(unsigned*)(Xs + (size_t)(t + 1) * S2 + dd) = (unsigned)b10 | ((unsigned)b11 << 16);
    }
    __syncthreads();

    {
        const int m0 = w * 32;
        f32x4 acc[2][8];
        #pragma unroll
        for (int mi = 0; mi < 2; mi++)
            #pragma unroll
            for (int ni = 0; ni < 8; ni++) acc[mi][ni] = (f32x4){0.f, 0.f, 0.f, 0.f};

        #pragma unroll
        for (int s = 0; s < 2; s++) {            // k0 = s*32
            bf16x8 av[2], bv[8];
            #pragma unroll
            for (int mi = 0; mi < 2; mi++)
                av[mi] = *(const bf16x8*)(XT + (m0 + mi * 16 + m) * ST1 + q * 8 + s * 32);
            #pragma unroll
            for (int ni = 0; ni < 8; ni++)
                bv[ni] = *(const bf16x8*)(XT + (ni * 16 + m) * ST1 + q * 8 + s * 32);
            #pragma unroll
            for (int mi = 0; mi < 2; mi++)
                #pragma unroll
                for (int ni = 0; ni < 8; ni++)
                    acc[mi][ni] = __builtin_amdgcn_mfma_f32_16x16x32_bf16(av[mi], bv[ni], acc[mi][ni], 0, 0, 0);
        }

        // Store partial G (bf16). C/D layout: col=lane&15, row=q*4+reg (m89/m91).
        unsigned short* pp = part + (size_t)blk * (D * D);
        #pragma unroll
        for (int mi = 0; mi < 2; mi++)
            #pragma unroll
            for (int ni = 0; ni < 8; ni++) {
                const int row0 = m0 + mi * 16 + q * 4;
                const int col = ni * 16 + m;
                #pragma unroll
                for (int r = 0; r < 4; r++)
                    pp[(size_t)(row0 + r) * D + col] = f2b(acc[mi][ni][r]);
            }
    }

    // Barrier 1: this batch's 64 partials are published.
    batch_barrier(ctr + b, 64u);

    // ---------------- Phase B: reduce bf16 partials -> bf16 G ----------------
    // Block blk reduces elements of its OWN batch (o>>14 == blk>>6 == b).
    {
        const int o = blk * 256 + tid;           // 0 .. BATCH*D*D
        const int e = o & 16383;
        const unsigned short* p = part + ((size_t)b * CHUNKS) * (D * D) + e;
        float s[8];
        #pragma unroll
        for (int i = 0; i < 8; i++) s[i] = 0.f;
        for (int c = 0; c < CHUNKS; c += 8) {
            #pragma unroll
            for (int i = 0; i < 8; i++)
                s[i] += b2f(p[(size_t)(c + i) * (D * D)]);
        }
        float sum = ((s[0] + s[1]) + (s[2] + s[3])) + ((s[4] + s[5]) + (s[6] + s[7]));
        g[o] = f2b(sum);
    }

    // Barrier 2: this batch's G is published (written by this batch's blocks).
    batch_barrier(ctr + 4 + b, 64u);

    // ---------------- Phase C: out = X * G via bf16 MFMA ----------------
    unsigned short* Gs = XG;    // overlays XT (dead since phase A)
    {
        const unsigned short* gp = g + (size_t)b * (D * D);
        const int f4 = tid & 15, r = tid >> 4;
        #pragma unroll
        for (int ii = 0; ii < 8; ii++) {
            const int row = r + ii * 16;
            uint4 gv = ((const uint4*)(gp + row * D))[f4];
            *(uint4*)(Gs + row * S2 + f4 * 8) = gv;
        }
    }
    __syncthreads();

    {
        f32x4 acc[8];
        #pragma unroll
        for (int ni = 0; ni < 8; ni++) acc[ni] = (f32x4){0.f, 0.f, 0.f, 0.f};

        const unsigned short* arow = Xs + (w * 16 + m) * S2 + q * 8;
        const unsigned short* brow = Gs + m * S2 + q * 8;

        #pragma unroll
        for (int s = 0; s < 4; s++) {
            bf16x8 a = *(const bf16x8*)(arow + s * 32);
            #pragma unroll
            for (int ni = 0; ni < 8; ni++) {
                bf16x8 bb = *(const bf16x8*)(brow + ni * 16 * S2 + s * 32);
                acc[ni] = __builtin_amdgcn_mfma_f32_16x16x32_bf16(a, bb, acc[ni], 0, 0, 0);
            }
        }

        float* op = out + ((size_t)b * T + (size_t)chunk * ROWS) * D;
        const int row0 = w * 16 + q * 4;
        #pragma unroll
        for (int ni = 0; ni < 8; ni++)
            #pragma unroll
            for (int r = 0; r < 4; r++)
                op[(row0 + r) * D + ni * 16 + m] = acc[ni][r];
    }
}

extern "C" void kernel_launch(void* const* d_in, const int* in_sizes, int n_in,
                              void* d_out, int out_size, void* d_ws, size_t ws_size,
                              hipStream_t stream) {
    const float* x = (const float*)d_in[0];
    float* out = (float*)d_out;

    const size_t part_elems = (size_t)BATCH * CHUNKS * D * D;   // 4.19M bf16 (8.4 MB)
    unsigned short* part = (unsigned short*)d_ws;
    unsigned short* g = part + part_elems;                      // bf16 G, 128 KB
    unsigned* ctr = (unsigned*)(g + (size_t)BATCH * D * D);     // 8 barrier counters

    // Workspace is re-poisoned each iteration -> counters must be zeroed.
    hipMemsetAsync(ctr, 0, 8 * sizeof(unsigned), stream);
    k_fused<<<BATCH * CHUNKS, 256, 0, stream>>>(x, part, g, ctr, out);
}

// Round 3
// 90.552 us; speedup vs baseline: 2.1140x; 1.3995x over previous
//
#include <hip/hip_runtime.h>

#define BATCH 4
#define T 4096
#define D 128
#define CHUNKS 64              // gram chunks per batch (64 rows each)
#define ROWS 64                // rows per block (gram and xg phases share the chunk)
#define ST1 72                 // XT LDS stride in ushorts (144 B = 36 words == 4 mod 32)
#define S2 136                 // row-major LDS stride in ushorts (272 B = 68 words == 4 mod 32)

typedef __attribute__((ext_vector_type(4))) float f32x4;
typedef __attribute__((ext_vector_type(8))) short bf16x8;

// float -> bf16 bits, round-to-nearest-even
__device__ __forceinline__ unsigned short f2b(float f) {
    unsigned u = __builtin_bit_cast(unsigned, f);
    u += 0x7FFFu + ((u >> 16) & 1u);
    return (unsigned short)(u >> 16);
}
__device__ __forceinline__ float b2f(unsigned short h) {
    return __builtin_bit_cast(float, (unsigned)h << 16);
}

// Tree barrier for one batch (64 blocks), all co-resident (1 block/CU).
// L1: 8 counters (one per 8-chunk group, 64-B spaced) -> max 8 serialized
// RMWs per line, parallel across groups. 8th arriver promotes to L2.
// Spin: RELAXED polls (no per-poll cache invalidate) + s_sleep backoff,
// then ONE acquire load. Release-sequence transitivity: arrival = RELEASE
// RMW on l1; promoter acquire-loads l1 (syncs with all 8 group releases)
// then RELEASE-RMWs l2; waiter's final acquire load of l2 syncs with all
// 8 promoters -> sees every block's prior global writes.
__device__ __forceinline__ void batch_barrier(unsigned* l1base, unsigned* l2, int grp) {
    __syncthreads();
    if (threadIdx.x == 0) {
        unsigned* l1 = l1base + grp * 16;
        unsigned old = __hip_atomic_fetch_add(l1, 1u, __ATOMIC_RELEASE, __HIP_MEMORY_SCOPE_AGENT);
        if (old == 7u) {
            (void)__hip_atomic_load(l1, __ATOMIC_ACQUIRE, __HIP_MEMORY_SCOPE_AGENT);
            __hip_atomic_fetch_add(l2, 1u, __ATOMIC_RELEASE, __HIP_MEMORY_SCOPE_AGENT);
        }
        while (__hip_atomic_load(l2, __ATOMIC_RELAXED, __HIP_MEMORY_SCOPE_AGENT) < 8u)
            __builtin_amdgcn_s_sleep(4);
        (void)__hip_atomic_load(l2, __ATOMIC_ACQUIRE, __HIP_MEMORY_SCOPE_AGENT);
    }
    __syncthreads();
}

// Single persistent kernel: 256 blocks x 256 threads, 1 block/CU.
// Phase A: partial Gram (proven k_gram) + row-major Xs staging piggybacked
//          on the same global loads (x read from HBM exactly once).
// Phase B: reduce 64 bf16 partials -> bf16 G (proven k_reduce_g, ILP=16).
// Phase C: out = X*G (proven k_xg_mfma), Xs already resident in LDS,
//          Gs overlays the XT region. Both inter-phase dependencies are
//          batch-local (64 blocks), handled by tree batch_barrier.
__global__ __launch_bounds__(256) void k_fused(const float* __restrict__ x,
                                               unsigned short* __restrict__ part,
                                               unsigned short* __restrict__ g,
                                               unsigned* __restrict__ ctr,
                                               float* __restrict__ out) {
    __shared__ unsigned short Xs[ROWS * S2];   // 17.0 KB, written phase A, read phase C
    __shared__ unsigned short XG[D * S2];      // 34.0 KB: XT (phase A) then Gs (phase C)

    const int blk = blockIdx.x;
    const int b = blk >> 6, chunk = blk & 63;
    const int grp = chunk >> 3;                // 8-chunk arrival group
    const float* xp = x + ((size_t)b * T + (size_t)chunk * ROWS) * D;
    const int tid = threadIdx.x;
    const int lane = tid & 63, w = tid >> 6;
    const int m = lane & 15, q = lane >> 4;

    // ---------------- Phase A: partial Gram via bf16 MFMA ----------------
    unsigned short* XT = XG;
    #pragma unroll
    for (int pass = 0; pass < 8; pass++) {
        const int slot = (tid >> 6) + 4 * pass;            // 0..31
        const int dd = 2 * (tid & 7) + 16 * (slot & 7);    // even d base, 0..126
        const int tpg = ((tid >> 3) & 7) + 8 * (slot >> 3);// t-pair 0..31
        const int t = 2 * tpg;
        float2 f0 = *(const float2*)(xp + (size_t)t * D + dd);
        float2 f1 = *(const float2*)(xp + (size_t)(t + 1) * D + dd);
        const unsigned short b00 = f2b(f0.x), b01 = f2b(f0.y);
        const unsigned short b10 = f2b(f1.x), b11 = f2b(f1.y);
        // transposed XT[d][t] for the Gram MFMA (banks: 2-way, free)
        *(unsigned*)(XT + dd * ST1 + 2 * tpg)       = (unsigned)b00 | ((unsigned)b10 << 16);
        *(unsigned*)(XT + (dd + 1) * ST1 + 2 * tpg) = (unsigned)b01 | ((unsigned)b11 << 16);
        // row-major Xs[t][d] for phase C (word = 136*tpg + dd/2 -> 2-way, free)
        *(unsigned*)(Xs + (size_t)t * S2 + dd)       = (unsigned)b00 | ((unsigned)b01 << 16);
        *(unsigned*)(Xs + (size_t)(t + 1) * S2 + dd) = (unsigned)b10 | ((unsigned)b11 << 16);
    }
    __syncthreads();

    {
        const int m0 = w * 32;
        f32x4 acc[2][8];
        #pragma unroll
        for (int mi = 0; mi < 2; mi++)
            #pragma unroll
            for (int ni = 0; ni < 8; ni++) acc[mi][ni] = (f32x4){0.f, 0.f, 0.f, 0.f};

        #pragma unroll
        for (int s = 0; s < 2; s++) {            // k0 = s*32
            bf16x8 av[2], bv[8];
            #pragma unroll
            for (int mi = 0; mi < 2; mi++)
                av[mi] = *(const bf16x8*)(XT + (m0 + mi * 16 + m) * ST1 + q * 8 + s * 32);
            #pragma unroll
            for (int ni = 0; ni < 8; ni++)
                bv[ni] = *(const bf16x8*)(XT + (ni * 16 + m) * ST1 + q * 8 + s * 32);
            #pragma unroll
            for (int mi = 0; mi < 2; mi++)
                #pragma unroll
                for (int ni = 0; ni < 8; ni++)
                    acc[mi][ni] = __builtin_amdgcn_mfma_f32_16x16x32_bf16(av[mi], bv[ni], acc[mi][ni], 0, 0, 0);
        }

        // Store partial G (bf16). C/D layout: col=lane&15, row=q*4+reg (m89/m91).
        unsigned short* pp = part + (size_t)blk * (D * D);
        #pragma unroll
        for (int mi = 0; mi < 2; mi++)
            #pragma unroll
            for (int ni = 0; ni < 8; ni++) {
                const int row0 = m0 + mi * 16 + q * 4;
                const int col = ni * 16 + m;
                #pragma unroll
                for (int r = 0; r < 4; r++)
                    pp[(size_t)(row0 + r) * D + col] = f2b(acc[mi][ni][r]);
            }
    }

    // Barrier 1: this batch's 64 partials are published.
    // ctr layout: l1[stage][batch][grp] at ((stage*4+b)*8+grp)*16,
    //             l2[stage][batch]     at (64 + stage*4 + b)*16  (64-B spaced)
    batch_barrier(ctr + ((0 * 4 + b) * 8) * 16, ctr + (64 + 0 * 4 + b) * 16, grp);

    // ---------------- Phase B: reduce bf16 partials -> bf16 G ----------------
    // Block blk reduces elements of its OWN batch (o>>14 == blk>>6 == b).
    {
        const int o = blk * 256 + tid;           // 0 .. BATCH*D*D
        const int e = o & 16383;
        const unsigned short* p = part + ((size_t)b * CHUNKS) * (D * D) + e;
        float s[16];
        #pragma unroll
        for (int i = 0; i < 16; i++) s[i] = 0.f;
        for (int c = 0; c < CHUNKS; c += 16) {
            #pragma unroll
            for (int i = 0; i < 16; i++)
                s[i] += b2f(p[(size_t)(c + i) * (D * D)]);
        }
        float t0 = ((s[0] + s[1]) + (s[2] + s[3])) + ((s[4] + s[5]) + (s[6] + s[7]));
        float t1 = ((s[8] + s[9]) + (s[10] + s[11])) + ((s[12] + s[13]) + (s[14] + s[15]));
        g[o] = f2b(t0 + t1);
    }

    // Barrier 2: this batch's G is published (written by this batch's blocks).
    batch_barrier(ctr + ((1 * 4 + b) * 8) * 16, ctr + (64 + 1 * 4 + b) * 16, grp);

    // ---------------- Phase C: out = X * G via bf16 MFMA ----------------
    unsigned short* Gs = XG;    // overlays XT (dead since phase A)
    {
        const unsigned short* gp = g + (size_t)b * (D * D);
        const int f4 = tid & 15, r = tid >> 4;
        #pragma unroll
        for (int ii = 0; ii < 8; ii++) {
            const int row = r + ii * 16;
            uint4 gv = ((const uint4*)(gp + row * D))[f4];
            *(uint4*)(Gs + row * S2 + f4 * 8) = gv;
        }
    }
    __syncthreads();

    {
        f32x4 acc[8];
        #pragma unroll
        for (int ni = 0; ni < 8; ni++) acc[ni] = (f32x4){0.f, 0.f, 0.f, 0.f};

        const unsigned short* arow = Xs + (w * 16 + m) * S2 + q * 8;
        const unsigned short* brow = Gs + m * S2 + q * 8;

        #pragma unroll
        for (int s = 0; s < 4; s++) {
            bf16x8 a = *(const bf16x8*)(arow + s * 32);
            #pragma unroll
            for (int ni = 0; ni < 8; ni++) {
                bf16x8 bb = *(const bf16x8*)(brow + ni * 16 * S2 + s * 32);
                acc[ni] = __builtin_amdgcn_mfma_f32_16x16x32_bf16(a, bb, acc[ni], 0, 0, 0);
            }
        }

        float* op = out + ((size_t)b * T + (size_t)chunk * ROWS) * D;
        const int row0 = w * 16 + q * 4;
        #pragma unroll
        for (int ni = 0; ni < 8; ni++)
            #pragma unroll
            for (int r = 0; r < 4; r++)
                op[(row0 + r) * D + ni * 16 + m] = acc[ni][r];
    }
}

extern "C" void kernel_launch(void* const* d_in, const int* in_sizes, int n_in,
                              void* d_out, int out_size, void* d_ws, size_t ws_size,
                              hipStream_t stream) {
    const float* x = (const float*)d_in[0];
    float* out = (float*)d_out;

    const size_t part_elems = (size_t)BATCH * CHUNKS * D * D;   // 4.19M bf16 (8.4 MB)
    unsigned short* part = (unsigned short*)d_ws;
    unsigned short* g = part + part_elems;                      // bf16 G, 128 KB
    unsigned* ctr = (unsigned*)(g + (size_t)BATCH * D * D);     // tree barrier counters

    // Workspace is re-poisoned each iteration -> counters must be zeroed.
    // 2 stages x 4 batches x (8 L1 + 1 L2) counters, 64-B spaced: 4608 B used.
    hipMemsetAsync(ctr, 0, 8192, stream);
    k_fused<<<BATCH * CHUNKS, 256, 0, stream>>>(x, part, g, ctr, out);
}

// Round 4
// 88.638 us; speedup vs baseline: 2.1596x; 1.0216x over previous
//
#include <hip/hip_runtime.h>

#define BATCH 4
#define T 4096
#define D 128
#define P 8                    // split-K partials per batch
#define KROWS 512              // rows per partial (T / P)
#define ROWS 64                // rows per staging chunk / per stage-2 block
#define ST1 72                 // XT LDS stride in ushorts (144 B = 36 words == 4 mod 32)
#define S2 136                 // row-major LDS stride in ushorts (272 B = 68 words == 4 mod 32)

typedef __attribute__((ext_vector_type(4))) float f32x4;
typedef __attribute__((ext_vector_type(8))) short bf16x8;

// float -> bf16 bits, round-to-nearest-even
__device__ __forceinline__ unsigned short f2b(float f) {
    unsigned u = __builtin_bit_cast(unsigned, f);
    u += 0x7FFFu + ((u >> 16) & 1u);
    return (unsigned short)(u >> 16);
}
__device__ __forceinline__ float b2f(unsigned short h) {
    return __builtin_bit_cast(float, (unsigned)h << 16);
}

// Proven phase-A staging: 64 rows x 128 cols f32 -> transposed bf16 XT[d][t].
// 8 passes x 256 threads x 16 B; banks <=2-way (free).
#define STAGE_CHUNK(XPBASE, DST)                                               \
    {                                                                          \
        _Pragma("unroll")                                                      \
        for (int pass = 0; pass < 8; pass++) {                                 \
            const int slot = (tid >> 6) + 4 * pass;                            \
            const int dd = 2 * (tid & 7) + 16 * (slot & 7);                    \
            const int tpg = ((tid >> 3) & 7) + 8 * (slot >> 3);                \
            const int t = 2 * tpg;                                             \
            float2 f0 = *(const float2*)((XPBASE) + (size_t)t * D + dd);       \
            float2 f1 = *(const float2*)((XPBASE) + (size_t)(t + 1) * D + dd); \
            unsigned u0 = (unsigned)f2b(f0.x) | ((unsigned)f2b(f1.x) << 16);   \
            unsigned u1 = (unsigned)f2b(f0.y) | ((unsigned)f2b(f1.y) << 16);   \
            *(unsigned*)((DST) + dd * ST1 + 2 * tpg) = u0;                     \
            *(unsigned*)((DST) + (dd + 1) * ST1 + 2 * tpg) = u1;               \
        }                                                                      \
    }

// ---------------- Kernel 1: split-K partial Gram, P=8 per batch ---------------
// 32 blocks x 256 threads; block (b,p) accumulates G over rows [p*512, p*512+512)
// in f32 MFMA acc (8 chunk iterations, double-buffered LDS, 1 sync/iter), then
// stores one bf16 128x128 partial. Same wave decomposition as the proven k_gram.
__global__ __launch_bounds__(256) void k_part(const float* __restrict__ x,
                                              unsigned short* __restrict__ part) {
    __shared__ unsigned short XT[2 * D * ST1];   // double-buffered, 36.9 KB
    const int blk = blockIdx.x;                  // 0..31
    const int b = blk >> 3, p = blk & 7;
    const float* xp = x + ((size_t)b * T + (size_t)p * KROWS) * D;
    const int tid = threadIdx.x;
    const int lane = tid & 63, w = tid >> 6;
    const int m = lane & 15, q = lane >> 4;
    const int m0 = w * 32;

    f32x4 acc[2][8];
    #pragma unroll
    for (int mi = 0; mi < 2; mi++)
        #pragma unroll
        for (int ni = 0; ni < 8; ni++) acc[mi][ni] = (f32x4){0.f, 0.f, 0.f, 0.f};

    STAGE_CHUNK(xp, XT);                         // chunk 0 -> buf 0
    __syncthreads();

    #pragma unroll
    for (int i = 0; i < 8; i++) {
        const unsigned short* cur = XT + (i & 1) * (D * ST1);
        if (i < 7) {                             // prefetch next chunk -> other buf
            unsigned short* nxt = XT + ((i + 1) & 1) * (D * ST1);
            const float* xn = xp + (size_t)(i + 1) * ROWS * D;
            STAGE_CHUNK(xn, nxt);
        }
        #pragma unroll
        for (int s = 0; s < 2; s++) {            // K=64 per chunk, 2 k-steps
            bf16x8 av[2], bv[8];
            #pragma unroll
            for (int mi = 0; mi < 2; mi++)
                av[mi] = *(const bf16x8*)(cur + (m0 + mi * 16 + m) * ST1 + q * 8 + s * 32);
            #pragma unroll
            for (int ni = 0; ni < 8; ni++)
                bv[ni] = *(const bf16x8*)(cur + (ni * 16 + m) * ST1 + q * 8 + s * 32);
            #pragma unroll
            for (int mi = 0; mi < 2; mi++)
                #pragma unroll
                for (int ni = 0; ni < 8; ni++)
                    acc[mi][ni] = __builtin_amdgcn_mfma_f32_16x16x32_bf16(av[mi], bv[ni], acc[mi][ni], 0, 0, 0);
        }
        __syncthreads();   // stage(i+1) visible before iter i+1; mfma(i) done before buf reuse
    }

    // Store partial (bf16). C/D layout: col=lane&15, row=q*4+reg (m89/m91).
    unsigned short* pp = part + (size_t)blk * (D * D);
    #pragma unroll
    for (int mi = 0; mi < 2; mi++)
        #pragma unroll
        for (int ni = 0; ni < 8; ni++) {
            const int row0 = m0 + mi * 16 + q * 4;
            const int col = ni * 16 + m;
            #pragma unroll
            for (int r = 0; r < 4; r++)
                pp[(size_t)(row0 + r) * D + col] = f2b(acc[mi][ni][r]);
        }
}

// ---------------- Kernel 2: fused 8-way reduce + out = X*G -------------------
// 256 blocks x 256 threads; block = (batch, 64-row chunk). Each block reduces
// its batch's 8 partials (256 KB, L2-resident under 2-XCD batch grouping)
// straight into the Gs LDS staging, then runs the proven k_xg MFMA phase.
__global__ __launch_bounds__(256) void k_xg2(const float* __restrict__ x,
                                             const unsigned short* __restrict__ part,
                                             float* __restrict__ out) {
    __shared__ unsigned short Xs[ROWS * S2];   // 17.4 KB
    __shared__ unsigned short Gs[D * S2];      // 34.8 KB
    const int blk = blockIdx.x;
    // batch -> 2 XCDs (blk%8 is the XCD heuristic): partials L2-resident per batch
    const int b = (blk & 7) >> 1;
    const int chunk = ((blk & 1) << 5) | (blk >> 3);   // 0..63, bijective per batch
    const float* xp = x + ((size_t)b * T + (size_t)chunk * ROWS) * D;
    const int tid = threadIdx.x;

    // Xs staging (proven): 64 rows f32 -> bf16 row-major
    {
        const int dg = tid & 31, tr = tid >> 5;
        #pragma unroll
        for (int ii = 0; ii < 8; ii++) {
            const int t = tr + ii * 8;
            float4 v = ((const float4*)(xp + (size_t)t * D))[dg];
            ushort4 pk;
            pk.x = f2b(v.x); pk.y = f2b(v.y); pk.z = f2b(v.z); pk.w = f2b(v.w);
            *(ushort4*)(Xs + t * S2 + dg * 4) = pk;
        }
    }
    // Gs staging fused with the 8-way partial reduction (f32 accumulate)
    {
        const unsigned short* pb = part + (size_t)b * P * (D * D);
        #pragma unroll
        for (int i = 0; i < 8; i++) {
            const int e8 = (i * 256 + tid) * 8;        // 8-elem group, coalesced
            float s[8];
            #pragma unroll
            for (int k = 0; k < 8; k++) s[k] = 0.f;
            #pragma unroll
            for (int pp = 0; pp < P; pp++) {
                uint4 v = *(const uint4*)(pb + (size_t)pp * (D * D) + e8);
                const unsigned uu[4] = {v.x, v.y, v.z, v.w};
                #pragma unroll
                for (int k = 0; k < 4; k++) {
                    s[2 * k]     += __builtin_bit_cast(float, uu[k] << 16);
                    s[2 * k + 1] += __builtin_bit_cast(float, uu[k] & 0xFFFF0000u);
                }
            }
            uint4 o;
            o.x = (unsigned)f2b(s[0]) | ((unsigned)f2b(s[1]) << 16);
            o.y = (unsigned)f2b(s[2]) | ((unsigned)f2b(s[3]) << 16);
            o.z = (unsigned)f2b(s[4]) | ((unsigned)f2b(s[5]) << 16);
            o.w = (unsigned)f2b(s[6]) | ((unsigned)f2b(s[7]) << 16);
            const int row = e8 >> 7, col = e8 & 127;
            *(uint4*)(Gs + row * S2 + col) = o;
        }
    }
    __syncthreads();

    // Proven k_xg MFMA phase: out(64x128) = Xs . G, B-fragment reads G row-major
    // exploiting G symmetry (G == G^T).
    {
        const int lane = tid & 63, w = tid >> 6;
        const int m = lane & 15, q = lane >> 4;
        f32x4 acc[8];
        #pragma unroll
        for (int ni = 0; ni < 8; ni++) acc[ni] = (f32x4){0.f, 0.f, 0.f, 0.f};

        const unsigned short* arow = Xs + (w * 16 + m) * S2 + q * 8;
        const unsigned short* brow = Gs + m * S2 + q * 8;

        #pragma unroll
        for (int s = 0; s < 4; s++) {
            bf16x8 a = *(const bf16x8*)(arow + s * 32);
            #pragma unroll
            for (int ni = 0; ni < 8; ni++) {
                bf16x8 bb = *(const bf16x8*)(brow + ni * 16 * S2 + s * 32);
                acc[ni] = __builtin_amdgcn_mfma_f32_16x16x32_bf16(a, bb, acc[ni], 0, 0, 0);
            }
        }

        float* op = out + ((size_t)b * T + (size_t)chunk * ROWS) * D;
        const int row0 = w * 16 + q * 4;
        #pragma unroll
        for (int ni = 0; ni < 8; ni++)
            #pragma unroll
            for (int r = 0; r < 4; r++)
                op[(row0 + r) * D + ni * 16 + m] = acc[ni][r];
    }
}

extern "C" void kernel_launch(void* const* d_in, const int* in_sizes, int n_in,
                              void* d_out, int out_size, void* d_ws, size_t ws_size,
                              hipStream_t stream) {
    const float* x = (const float*)d_in[0];
    float* out = (float*)d_out;

    // Workspace: 4 batches x 8 partials x 128x128 bf16 = 1 MB. No counters,
    // no memset, no barriers — the kernel boundary is the sync.
    unsigned short* part = (unsigned short*)d_ws;

    k_part<<<BATCH * P, 256, 0, stream>>>(x, part);
    k_xg2<<<BATCH * 64, 256, 0, stream>>>(x, part, out);
}

// Round 5
// 80.563 us; speedup vs baseline: 2.3761x; 1.1002x over previous
//
#include <hip/hip_runtime.h>

#define BATCH 4
#define T 4096
#define D 128
#define P 8                    // split-K partials per batch
#define KROWS 512              // rows per partial (T / P)
#define ROWS 64                // rows per staging chunk / per stage-2 block
#define ST1 72                 // XT LDS stride in ushorts (144 B = 36 words == 4 mod 32)
#define S2 136                 // row-major LDS stride in ushorts (272 B = 68 words == 4 mod 32)

typedef __attribute__((ext_vector_type(4))) float f32x4;
typedef __attribute__((ext_vector_type(8))) short bf16x8;

// float -> bf16 bits, round-to-nearest-even
__device__ __forceinline__ unsigned short f2b(float f) {
    unsigned u = __builtin_bit_cast(unsigned, f);
    u += 0x7FFFu + ((u >> 16) & 1u);
    return (unsigned short)(u >> 16);
}

// Proven phase-A staging: 64 rows x 128 cols f32 -> transposed bf16 XT[d][t].
// 8 passes x 256 threads x 16 B; banks <=2-way (free).
#define STAGE_CHUNK(XPBASE, DST)                                               \
    {                                                                          \
        _Pragma("unroll")                                                      \
        for (int pass = 0; pass < 8; pass++) {                                 \
            const int slot = (tid >> 6) + 4 * pass;                            \
            const int dd = 2 * (tid & 7) + 16 * (slot & 7);                    \
            const int tpg = ((tid >> 3) & 7) + 8 * (slot >> 3);                \
            const int t = 2 * tpg;                                             \
            float2 f0 = *(const float2*)((XPBASE) + (size_t)t * D + dd);       \
            float2 f1 = *(const float2*)((XPBASE) + (size_t)(t + 1) * D + dd); \
            unsigned u0 = (unsigned)f2b(f0.x) | ((unsigned)f2b(f1.x) << 16);   \
            unsigned u1 = (unsigned)f2b(f0.y) | ((unsigned)f2b(f1.y) << 16);   \
            *(unsigned*)((DST) + dd * ST1 + 2 * tpg) = u0;                     \
            *(unsigned*)((DST) + (dd + 1) * ST1 + 2 * tpg) = u1;               \
        }                                                                      \
    }

// ---------------- Kernel 1: split-K partial Gram, P=8 per batch ---------------
// 32 blocks x 256 threads; block (b,p) accumulates G over rows [p*512, p*512+512)
// in f32 MFMA acc. Chunk loop is a RUNTIME loop (#pragma unroll 1) with
// pointer-swapped double buffer: live state ~ acc(64) + packs(16) + frags(40)
// VGPRs -> no spill (R4's full unroll was the suspected scratch-spill source).
__global__ __launch_bounds__(256) void k_part(const float* __restrict__ x,
                                              unsigned short* __restrict__ part) {
    __shared__ unsigned short XT[2 * D * ST1];   // double-buffered, 36.9 KB
    const int blk = blockIdx.x;                  // 0..31
    const int b = blk >> 3, p = blk & 7;
    const float* xp = x + ((size_t)b * T + (size_t)p * KROWS) * D;
    const int tid = threadIdx.x;
    const int lane = tid & 63, w = tid >> 6;
    const int m = lane & 15, q = lane >> 4;
    const int m0 = w * 32;

    f32x4 acc[2][8];
    #pragma unroll
    for (int mi = 0; mi < 2; mi++)
        #pragma unroll
        for (int ni = 0; ni < 8; ni++) acc[mi][ni] = (f32x4){0.f, 0.f, 0.f, 0.f};

    STAGE_CHUNK(xp, XT);                         // chunk 0 -> buf 0
    __syncthreads();

    #pragma unroll 1
    for (int i = 0; i < 8; i++) {
        const unsigned short* cur = XT + (i & 1) * (D * ST1);
        unsigned short* nxt = XT + ((i + 1) & 1) * (D * ST1);
        if (i < 7) {                             // prefetch next chunk -> other buf
            const float* xn = xp + (size_t)(i + 1) * ROWS * D;
            STAGE_CHUNK(xn, nxt);
        }
        #pragma unroll
        for (int s = 0; s < 2; s++) {            // K=64 per chunk, 2 k-steps
            bf16x8 av[2], bv[8];
            #pragma unroll
            for (int mi = 0; mi < 2; mi++)
                av[mi] = *(const bf16x8*)(cur + (m0 + mi * 16 + m) * ST1 + q * 8 + s * 32);
            #pragma unroll
            for (int ni = 0; ni < 8; ni++)
                bv[ni] = *(const bf16x8*)(cur + (ni * 16 + m) * ST1 + q * 8 + s * 32);
            #pragma unroll
            for (int mi = 0; mi < 2; mi++)
                #pragma unroll
                for (int ni = 0; ni < 8; ni++)
                    acc[mi][ni] = __builtin_amdgcn_mfma_f32_16x16x32_bf16(av[mi], bv[ni], acc[mi][ni], 0, 0, 0);
        }
        __syncthreads();   // stage(i+1) visible before iter i+1; reads of cur done before overwrite
    }

    // Store partial (bf16). C/D layout: col=lane&15, row=q*4+reg (m89/m91).
    unsigned short* pp = part + (size_t)blk * (D * D);
    #pragma unroll
    for (int mi = 0; mi < 2; mi++)
        #pragma unroll
        for (int ni = 0; ni < 8; ni++) {
            const int row0 = m0 + mi * 16 + q * 4;
            const int col = ni * 16 + m;
            #pragma unroll
            for (int r = 0; r < 4; r++)
                pp[(size_t)(row0 + r) * D + col] = f2b(acc[mi][ni][r]);
        }
}

// ---------------- Kernel 2: fused 8-way reduce + out = X*G -------------------
// (verbatim from R4 — passed; theory says it is NOT the bottleneck)
// 256 blocks x 256 threads; block = (batch, 64-row chunk). Each block reduces
// its batch's 8 partials (256 KB, L2-resident under 2-XCD batch grouping)
// straight into the Gs LDS staging, then runs the proven k_xg MFMA phase.
__global__ __launch_bounds__(256) void k_xg2(const float* __restrict__ x,
                                             const unsigned short* __restrict__ part,
                                             float* __restrict__ out) {
    __shared__ unsigned short Xs[ROWS * S2];   // 17.4 KB
    __shared__ unsigned short Gs[D * S2];      // 34.8 KB
    const int blk = blockIdx.x;
    // batch -> 2 XCDs (blk%8 is the XCD heuristic): partials L2-resident per batch
    const int b = (blk & 7) >> 1;
    const int chunk = ((blk & 1) << 5) | (blk >> 3);   // 0..63, bijective per batch
    const float* xp = x + ((size_t)b * T + (size_t)chunk * ROWS) * D;
    const int tid = threadIdx.x;

    // Xs staging (proven): 64 rows f32 -> bf16 row-major
    {
        const int dg = tid & 31, tr = tid >> 5;
        #pragma unroll
        for (int ii = 0; ii < 8; ii++) {
            const int t = tr + ii * 8;
            float4 v = ((const float4*)(xp + (size_t)t * D))[dg];
            ushort4 pk;
            pk.x = f2b(v.x); pk.y = f2b(v.y); pk.z = f2b(v.z); pk.w = f2b(v.w);
            *(ushort4*)(Xs + t * S2 + dg * 4) = pk;
        }
    }
    // Gs staging fused with the 8-way partial reduction (f32 accumulate)
    {
        const unsigned short* pb = part + (size_t)b * P * (D * D);
        #pragma unroll
        for (int i = 0; i < 8; i++) {
            const int e8 = (i * 256 + tid) * 8;        // 8-elem group, coalesced
            float s[8];
            #pragma unroll
            for (int k = 0; k < 8; k++) s[k] = 0.f;
            #pragma unroll
            for (int pp = 0; pp < P; pp++) {
                uint4 v = *(const uint4*)(pb + (size_t)pp * (D * D) + e8);
                const unsigned uu[4] = {v.x, v.y, v.z, v.w};
                #pragma unroll
                for (int k = 0; k < 4; k++) {
                    s[2 * k]     += __builtin_bit_cast(float, uu[k] << 16);
                    s[2 * k + 1] += __builtin_bit_cast(float, uu[k] & 0xFFFF0000u);
                }
            }
            uint4 o;
            o.x = (unsigned)f2b(s[0]) | ((unsigned)f2b(s[1]) << 16);
            o.y = (unsigned)f2b(s[2]) | ((unsigned)f2b(s[3]) << 16);
            o.z = (unsigned)f2b(s[4]) | ((unsigned)f2b(s[5]) << 16);
            o.w = (unsigned)f2b(s[6]) | ((unsigned)f2b(s[7]) << 16);
            const int row = e8 >> 7, col = e8 & 127;
            *(uint4*)(Gs + row * S2 + col) = o;
        }
    }
    __syncthreads();

    // Proven k_xg MFMA phase: out(64x128) = Xs . G, B-fragment reads G row-major
    // exploiting G symmetry (G == G^T).
    {
        const int lane = tid & 63, w = tid >> 6;
        const int m = lane & 15, q = lane >> 4;
        f32x4 acc[8];
        #pragma unroll
        for (int ni = 0; ni < 8; ni++) acc[ni] = (f32x4){0.f, 0.f, 0.f, 0.f};

        const unsigned short* arow = Xs + (w * 16 + m) * S2 + q * 8;
        const unsigned short* brow = Gs + m * S2 + q * 8;

        #pragma unroll
        for (int s = 0; s < 4; s++) {
            bf16x8 a = *(const bf16x8*)(arow + s * 32);
            #pragma unroll
            for (int ni = 0; ni < 8; ni++) {
                bf16x8 bb = *(const bf16x8*)(brow + ni * 16 * S2 + s * 32);
                acc[ni] = __builtin_amdgcn_mfma_f32_16x16x32_bf16(a, bb, acc[ni], 0, 0, 0);
            }
        }

        float* op = out + ((size_t)b * T + (size_t)chunk * ROWS) * D;
        const int row0 = w * 16 + q * 4;
        #pragma unroll
        for (int ni = 0; ni < 8; ni++)
            #pragma unroll
            for (int r = 0; r < 4; r++)
                op[(row0 + r) * D + ni * 16 + m] = acc[ni][r];
    }
}

extern "C" void kernel_launch(void* const* d_in, const int* in_sizes, int n_in,
                              void* d_out, int out_size, void* d_ws, size_t ws_size,
                              hipStream_t stream) {
    const float* x = (const float*)d_in[0];
    float* out = (float*)d_out;

    // Workspace: 4 batches x 8 partials x 128x128 bf16 = 1 MB. No counters,
    // no memset, no barriers — the kernel boundary is the sync.
    unsigned short* part = (unsigned short*)d_ws;

    k_part<<<BATCH * P, 256, 0, stream>>>(x, part);
    k_xg2<<<BATCH * 64, 256, 0, stream>>>(x, part, out);
}

// Round 6
// 70.866 us; speedup vs baseline: 2.7012x; 1.1368x over previous
//
#include <hip/hip_runtime.h>

#define BATCH 4
#define T 4096
#define D 128
#define CHUNKS 64              // gram chunks per batch (64 rows each)
#define ROWS1 64               // rows per gram block
#define ROWS2 32               // rows per stage-2 block (512 blocks -> 2 blocks/CU)
#define ST1 72                 // XT LDS stride in ushorts (144 B = 36 words == 4 mod 32)
#define S2 136                 // stage-2 LDS stride in ushorts (272 B)

typedef __attribute__((ext_vector_type(4))) float f32x4;
typedef __attribute__((ext_vector_type(8))) short bf16x8;

// float -> bf16 bits, round-to-nearest-even
__device__ __forceinline__ unsigned short f2b(float f) {
    unsigned u = __builtin_bit_cast(unsigned, f);
    u += 0x7FFFu + ((u >> 16) & 1u);
    return (unsigned short)(u >> 16);
}
__device__ __forceinline__ float b2f(unsigned short h) {
    return __builtin_bit_cast(float, (unsigned)h << 16);
}

// ---------------- Stage 1: partial Gram via bf16 MFMA -----------------
// (verbatim R0 — proven) 256 blocks x 256 threads; block = (batch, 64-row chunk).
__global__ __launch_bounds__(256) void k_gram(const float* __restrict__ x,
                                              unsigned short* __restrict__ part) {
    __shared__ unsigned short XT[D * ST1];   // 18.4 KB
    const int blk = blockIdx.x;
    const int b = blk >> 6, chunk = blk & 63;
    const float* xp = x + ((size_t)b * T + (size_t)chunk * ROWS1) * D;
    const int tid = threadIdx.x;

    #pragma unroll
    for (int pass = 0; pass < 8; pass++) {
        const int slot = (tid >> 6) + 4 * pass;      // 0..31
        const int dd = 2 * (tid & 7) + 16 * (slot & 7);    // even d base, 0..126
        const int tpg = ((tid >> 3) & 7) + 8 * (slot >> 3); // t-pair 0..31
        const int t = 2 * tpg;
        float2 f0 = *(const float2*)(xp + (size_t)t * D + dd);
        float2 f1 = *(const float2*)(xp + (size_t)(t + 1) * D + dd);
        unsigned u0 = (unsigned)f2b(f0.x) | ((unsigned)f2b(f1.x) << 16);
        unsigned u1 = (unsigned)f2b(f0.y) | ((unsigned)f2b(f1.y) << 16);
        *(unsigned*)(XT + dd * ST1 + 2 * tpg) = u0;        // XT[dd][t..t+1]
        *(unsigned*)(XT + (dd + 1) * ST1 + 2 * tpg) = u1;  // XT[dd+1][t..t+1]
    }
    __syncthreads();

    const int lane = tid & 63, w = tid >> 6;
    const int m = lane & 15, q = lane >> 4;
    const int m0 = w * 32;

    f32x4 acc[2][8];
    #pragma unroll
    for (int mi = 0; mi < 2; mi++)
        #pragma unroll
        for (int ni = 0; ni < 8; ni++) acc[mi][ni] = (f32x4){0.f, 0.f, 0.f, 0.f};

    #pragma unroll
    for (int s = 0; s < 2; s++) {            // k0 = s*32
        bf16x8 av[2], bv[8];
        #pragma unroll
        for (int mi = 0; mi < 2; mi++)
            av[mi] = *(const bf16x8*)(XT + (m0 + mi * 16 + m) * ST1 + q * 8 + s * 32);
        #pragma unroll
        for (int ni = 0; ni < 8; ni++)
            bv[ni] = *(const bf16x8*)(XT + (ni * 16 + m) * ST1 + q * 8 + s * 32);
        #pragma unroll
        for (int mi = 0; mi < 2; mi++)
            #pragma unroll
            for (int ni = 0; ni < 8; ni++)
                acc[mi][ni] = __builtin_amdgcn_mfma_f32_16x16x32_bf16(av[mi], bv[ni], acc[mi][ni], 0, 0, 0);
    }

    // Store partial G (bf16). C/D layout: col=lane&15, row=q*4+reg (m89/m91).
    unsigned short* pp = part + (size_t)blk * (D * D);
    #pragma unroll
    for (int mi = 0; mi < 2; mi++)
        #pragma unroll
        for (int ni = 0; ni < 8; ni++) {
            const int row0 = m0 + mi * 16 + q * 4;
            const int col = ni * 16 + m;
            #pragma unroll
            for (int r = 0; r < 4; r++)
                pp[(size_t)(row0 + r) * D + col] = f2b(acc[mi][ni][r]);
        }
}

// ---------------- Stage 1b: reduce bf16 partials -> bf16 G -----------------
// (verbatim R0 — proven) 256 blocks x 256 threads; one G element/thread.
__global__ __launch_bounds__(256) void k_reduce_g(const unsigned short* __restrict__ part,
                                                  unsigned short* __restrict__ g) {
    const int o = blockIdx.x * 256 + threadIdx.x;   // 0 .. BATCH*D*D
    const int b = o >> 14;
    const int e = o & 16383;
    const unsigned short* p = part + ((size_t)b * CHUNKS) * (D * D) + e;
    float s[8];
    #pragma unroll
    for (int i = 0; i < 8; i++) s[i] = 0.f;
    for (int c = 0; c < CHUNKS; c += 8) {
        #pragma unroll
        for (int i = 0; i < 8; i++)
            s[i] += b2f(p[(size_t)(c + i) * (D * D)]);
    }
    float sum = ((s[0] + s[1]) + (s[2] + s[3])) + ((s[4] + s[5]) + (s[6] + s[7]));
    g[o] = f2b(sum);
}

// ---------------- Stage 2: out = X * G via bf16 MFMA -----------------
// CHANGED vs R0: 512 blocks x 32 rows (was 256 x 64) -> 2 blocks/CU.
// LDS 8.7 + 34.8 = 43.5 KB -> LDS-fit 3 blocks/CU; grid gives 2. One block's
// staging (global-load latency) overlaps the other's MFMA + stores.
// Wave w: m-tile (w&1), n-half (w>>1); 16 MFMA/wave, acc 4 x f32x4.
__global__ __launch_bounds__(256) void k_xg_mfma(const float* __restrict__ x,
                                                 const unsigned short* __restrict__ g,
                                                 float* __restrict__ out) {
    __shared__ unsigned short Xs[ROWS2 * S2];   // 8.7 KB
    __shared__ unsigned short Gs[D * S2];       // 34.8 KB
    const int blk = blockIdx.x;
    const int b = blk >> 7, chunk = blk & 127;
    const float* xp = x + ((size_t)b * T + (size_t)chunk * ROWS2) * D;
    const unsigned short* gp = g + (size_t)b * (D * D);
    const int tid = threadIdx.x;

    {   // Xs staging: 32 rows f32 -> bf16 row-major (4 passes of 8 rows)
        const int dg = tid & 31, tr = tid >> 5;
        #pragma unroll
        for (int ii = 0; ii < 4; ii++) {
            const int t = tr + ii * 8;
            float4 v = ((const float4*)(xp + (size_t)t * D))[dg];
            ushort4 pk;
            pk.x = f2b(v.x); pk.y = f2b(v.y); pk.z = f2b(v.z); pk.w = f2b(v.w);
            *(ushort4*)(Xs + t * S2 + dg * 4) = pk;
        }
    }
    {   // Gs staging: full 128x128 bf16 G (proven R0 pattern)
        const int f4 = tid & 15, r = tid >> 4;
        #pragma unroll
        for (int ii = 0; ii < 8; ii++) {
            const int row = r + ii * 16;
            uint4 gv = ((const uint4*)(gp + row * D))[f4];
            *(uint4*)(Gs + row * S2 + f4 * 8) = gv;
        }
    }
    __syncthreads();

    const int lane = tid & 63, w = tid >> 6;
    const int m = lane & 15, q = lane >> 4;
    const int mt = w & 1;       // m-tile within the 32 rows
    const int nh = w >> 1;      // n-half: 4 n-tiles each

    f32x4 acc[4];
    #pragma unroll
    for (int ni = 0; ni < 4; ni++) acc[ni] = (f32x4){0.f, 0.f, 0.f, 0.f};

    const unsigned short* arow = Xs + (mt * 16 + m) * S2 + q * 8;
    const unsigned short* brow = Gs + m * S2 + q * 8;

    #pragma unroll
    for (int s = 0; s < 4; s++) {
        bf16x8 a = *(const bf16x8*)(arow + s * 32);
        #pragma unroll
        for (int ni = 0; ni < 4; ni++) {
            bf16x8 bb = *(const bf16x8*)(brow + (nh * 4 + ni) * 16 * S2 + s * 32);
            acc[ni] = __builtin_amdgcn_mfma_f32_16x16x32_bf16(a, bb, acc[ni], 0, 0, 0);
        }
    }

    float* op = out + ((size_t)b * T + (size_t)chunk * ROWS2) * D;
    const int row0 = mt * 16 + q * 4;
    #pragma unroll
    for (int ni = 0; ni < 4; ni++)
        #pragma unroll
        for (int r = 0; r < 4; r++)
            op[(row0 + r) * D + (nh * 4 + ni) * 16 + m] = acc[ni][r];
}

extern "C" void kernel_launch(void* const* d_in, const int* in_sizes, int n_in,
                              void* d_out, int out_size, void* d_ws, size_t ws_size,
                              hipStream_t stream) {
    const float* x = (const float*)d_in[0];
    float* out = (float*)d_out;

    const size_t part_elems = (size_t)BATCH * CHUNKS * D * D;     // 4.19M bf16 (8.4 MB)
    unsigned short* part = (unsigned short*)d_ws;
    unsigned short* g = part + part_elems;                        // bf16 G, 128 KB

    k_gram<<<BATCH * CHUNKS, 256, 0, stream>>>(x, part);
    k_reduce_g<<<BATCH * D * D / 256, 256, 0, stream>>>(part, g);
    k_xg_mfma<<<BATCH * 128, 256, 0, stream>>>(x, g, out);
}